// Round 1
// 349.790 us; speedup vs baseline: 1.2609x; 1.2609x over previous
//
#include <hip/hip_runtime.h>
#include <hip/hip_bf16.h>

#define N_NODES 8192
#define F_IN    128
#define F_OUT   64
#define N_EDGES 262144

typedef unsigned int   u32;
typedef unsigned short u16;
typedef __attribute__((ext_vector_type(8))) short short8;
typedef __attribute__((ext_vector_type(4))) float f32x4;

__device__ __forceinline__ u16 f2bf_rne(float f) {
    u32 u = __float_as_uint(f);
    u32 r = (u + 0x7FFFu + ((u >> 16) & 1u)) >> 16;
    return (u16)r;
}
__device__ __forceinline__ float bf2f(u16 b) {
    return __uint_as_float(((u32)b) << 16);
}

// ---------------------------------------------------------------------------
// Detect edge_index width: int64 => all odd 32-bit words zero (ids < 8192).
// ---------------------------------------------------------------------------
__global__ __launch_bounds__(256) void detect_ei_kernel(const int* __restrict__ ei,
                                                        int* __restrict__ eflag) {
    int i = blockIdx.x * 256 + threadIdx.x;          // 8192 samples
    if (ei[2 * i + 1] != 0) atomicOr(eflag, 1);
}

// ---------------------------------------------------------------------------
// Detect x dtype (hedge; expected fp32). xdt = 1 => bf16, 0 => fp32.
// ---------------------------------------------------------------------------
__global__ __launch_bounds__(256) void detect_xdt_kernel(const u32* __restrict__ xw,
                                                         int* __restrict__ xdt) {
    __shared__ int cnt;
    if (threadIdx.x == 0) cnt = 0;
    __syncthreads();
    u32 w = xw[threadIdx.x * 64 + 1];
    u32 e = (w >> 7) & 0xFFu;
    if (e >= 100u && e <= 134u) atomicAdd(&cnt, 1);
    __syncthreads();
    if (threadIdx.x == 0) *xdt = (cnt > 128) ? 1 : 0;
}

// deg[d] = count of incoming edges (self loop added later as +1)
__global__ __launch_bounds__(256) void deg_kernel(const int* __restrict__ ei,
                                                  const int* __restrict__ eflagp,
                                                  int* __restrict__ deg) {
    int e = blockIdx.x * 256 + threadIdx.x;
    bool is64 = (*eflagp == 0);
    int d = is64 ? ei[2 * (N_EDGES + e)] : ei[N_EDGES + e];
    atomicAdd(&deg[d], 1);
}

// ---------------------------------------------------------------------------
// Exclusive prefix sum over deg[8192] -> offs[8193]; cursor = copy of offs.
// One block of 1024 threads, 8 elements each, Hillis-Steele block scan.
// ---------------------------------------------------------------------------
__global__ __launch_bounds__(1024) void scan_kernel(const int* __restrict__ deg,
                                                    int* __restrict__ offs,
                                                    int* __restrict__ cursor) {
    __shared__ int part[1024];
    int t = threadIdx.x;
    int loc[8];
    int run = 0;
    #pragma unroll
    for (int j = 0; j < 8; ++j) { loc[j] = run; run += deg[t * 8 + j]; }
    part[t] = run;
    __syncthreads();
    for (int d = 1; d < 1024; d <<= 1) {
        int v = (t >= d) ? part[t - d] : 0;
        __syncthreads();
        part[t] += v;
        __syncthreads();
    }
    int pre = part[t] - run;                 // exclusive prefix of this chunk
    #pragma unroll
    for (int j = 0; j < 8; ++j) {
        int v = pre + loc[j];
        offs[t * 8 + j]   = v;
        cursor[t * 8 + j] = v;
    }
    if (t == 1023) offs[8192] = pre + run;   // == N_EDGES
}

// ---------------------------------------------------------------------------
// Bucket edges by dst: esrc[offs[d]..offs[d+1]) = list of srcs into d.
// ---------------------------------------------------------------------------
__global__ __launch_bounds__(256) void fill_kernel(const int* __restrict__ ei,
                                                   const int* __restrict__ eflagp,
                                                   int* __restrict__ cursor,
                                                   int* __restrict__ esrc) {
    int e = blockIdx.x * 256 + threadIdx.x;
    bool is64 = (*eflagp == 0);
    int s = is64 ? ei[2 * e]             : ei[e];
    int d = is64 ? ei[2 * (N_EDGES + e)] : ei[N_EDGES + e];
    int pos = atomicAdd(&cursor[d], 1);
    esrc[pos] = s;
}

// ---------------------------------------------------------------------------
// h_scaled = dinv * (x^T W), z = b + dinv * h_scaled  (self-loop folded).
// 65536 threads: og = id>>13 (uniform per block), n = id & 8191 (coalesced).
// ---------------------------------------------------------------------------
__global__ __launch_bounds__(256) void feat_kernel(
        const void* __restrict__ xv, const void* __restrict__ Wv,
        const void* __restrict__ bv, const int* __restrict__ xdtp,
        const int* __restrict__ deg,
        float* __restrict__ dinv,
        float* __restrict__ h,                  // [N][64], pre-scaled by dinv[n]
        float* __restrict__ z)                  // [N][64]
{
    __shared__ float Wl[F_IN * F_OUT];          // 32 KB
    const bool isbf = (*xdtp != 0);
    int t = threadIdx.x;
    if (isbf) {
        const __hip_bfloat16* Wb = (const __hip_bfloat16*)Wv;
        for (int i = t; i < F_IN * F_OUT; i += 256) Wl[i] = (float)Wb[i];
    } else {
        const float* Wf = (const float*)Wv;
        for (int i = t; i < F_IN * F_OUT; i += 256) Wl[i] = Wf[i];
    }
    __syncthreads();

    int id = blockIdx.x * 256 + t;              // 0..65535
    int og = id >> 13;                          // 0..7, uniform within block
    int n  = id & (N_NODES - 1);

    float dv = rsqrtf((float)(deg[n] + 1));
    float acc[8] = {0.f,0.f,0.f,0.f,0.f,0.f,0.f,0.f};

    if (isbf) {
        const __hip_bfloat16* xb = (const __hip_bfloat16*)xv;
        for (int f = 0; f < F_IN; ++f) {
            float xval = (float)xb[f * N_NODES + n];
            const float4* w4 = (const float4*)&Wl[f * F_OUT + og * 8];
            float4 w0 = w4[0], w1 = w4[1];
            acc[0] += xval * w0.x; acc[1] += xval * w0.y;
            acc[2] += xval * w0.z; acc[3] += xval * w0.w;
            acc[4] += xval * w1.x; acc[5] += xval * w1.y;
            acc[6] += xval * w1.z; acc[7] += xval * w1.w;
        }
    } else {
        const float* xf = (const float*)xv;
        for (int f = 0; f < F_IN; ++f) {
            float xval = xf[f * N_NODES + n];
            const float4* w4 = (const float4*)&Wl[f * F_OUT + og * 8];
            float4 w0 = w4[0], w1 = w4[1];
            acc[0] += xval * w0.x; acc[1] += xval * w0.y;
            acc[2] += xval * w0.z; acc[3] += xval * w0.w;
            acc[4] += xval * w1.x; acc[5] += xval * w1.y;
            acc[6] += xval * w1.z; acc[7] += xval * w1.w;
        }
    }

    if (og == 0) dinv[n] = dv;

    float hs[8], zb[8];
    float bvals[8];
    if (isbf) {
        const __hip_bfloat16* bb = (const __hip_bfloat16*)bv;
        #pragma unroll
        for (int j = 0; j < 8; ++j) bvals[j] = (float)bb[og * 8 + j];
    } else {
        const float* bf = (const float*)bv;
        #pragma unroll
        for (int j = 0; j < 8; ++j) bvals[j] = bf[og * 8 + j];
    }
    #pragma unroll
    for (int j = 0; j < 8; ++j) {
        hs[j] = dv * acc[j];                    // pre-scaled message
        zb[j] = bvals[j] + dv * hs[j];          // self-loop term
    }
    float* hp = h + (size_t)n * 64 + og * 8;
    ((float4*)hp)[0] = make_float4(hs[0], hs[1], hs[2], hs[3]);
    ((float4*)hp)[1] = make_float4(hs[4], hs[5], hs[6], hs[7]);
    float* zp = z + (size_t)n * 64 + og * 8;
    ((float4*)zp)[0] = make_float4(zb[0], zb[1], zb[2], zb[3]);
    ((float4*)zp)[1] = make_float4(zb[4], zb[5], zb[6], zb[7]);
}

// ---------------------------------------------------------------------------
// Gather aggregation: one wave per dst node, no atomics.
// z[d] += dinv[d] * sum_{s in in(d)} h_scaled[s]
// ---------------------------------------------------------------------------
__global__ __launch_bounds__(256) void gather_kernel(
        const int* __restrict__ offs, const int* __restrict__ esrc,
        const float* __restrict__ h, const float* __restrict__ dinv,
        float* __restrict__ z)
{
    int t = blockIdx.x * 256 + threadIdx.x;
    int d = t >> 6;
    int o = t & 63;
    int beg = offs[d], end = offs[d + 1];
    float acc = 0.f;
    for (int i = beg; i < end; ++i) {
        int s = esrc[i];                         // wave-uniform
        acc += h[(size_t)s * 64 + o];            // coalesced 256B row
    }
    z[(size_t)d * 64 + o] += dinv[d] * acc;
}

// ---------------------------------------------------------------------------
// out = sigmoid(z @ z^T) via split-bf16 MFMA (AhBh + AhBl + AlBh), fp32 out.
// 128x128 tile / block, K=64 in one LDS stage (no K loop). 4 waves, each
// owning 32x128. XOR-16B swizzle on LDS rows (128B stride) kills the
// 32-way ds_read_b128 bank conflict (Guideline 4).
// ---------------------------------------------------------------------------
__global__ __launch_bounds__(256) void gemm_sig_kernel(
        const float* __restrict__ z, float* __restrict__ out)
{
    __shared__ u16 Ah[128][64];   // 16 KB each; 64 KB total
    __shared__ u16 Al[128][64];
    __shared__ u16 Bh[128][64];
    __shared__ u16 Bl[128][64];

    int t  = threadIdx.x;
    int i0 = blockIdx.x * 128;
    int j0 = blockIdx.y * 128;

    // ---- stage: 2048 items (2 tiles x 128 rows x 8 chunks of 8 floats) ----
    #pragma unroll
    for (int it = 0; it < 8; ++it) {
        int item = it * 256 + t;              // 0..2047
        int tile = item >> 10;                // 0: A(i0), 1: B(j0)
        int r    = (item >> 3) & 127;
        int c    = item & 7;                  // 8-float chunk -> 16B of bf16
        const float* src = z + (size_t)((tile ? j0 : i0) + r) * 64 + c * 8;
        float4 v0 = ((const float4*)src)[0];
        float4 v1 = ((const float4*)src)[1];
        float vf[8] = {v0.x, v0.y, v0.z, v0.w, v1.x, v1.y, v1.z, v1.w};
        short8 sh, sl;
        #pragma unroll
        for (int j = 0; j < 8; ++j) {
            float f  = vf[j];
            u16 hb   = f2bf_rne(f);
            u16 lb   = f2bf_rne(f - bf2f(hb));
            sh[j] = (short)hb;
            sl[j] = (short)lb;
        }
        int cs = c ^ (r & 7);                 // XOR swizzle within row
        u16* dh = tile ? &Bh[r][cs * 8] : &Ah[r][cs * 8];
        u16* dl = tile ? &Bl[r][cs * 8] : &Al[r][cs * 8];
        *(short8*)dh = sh;
        *(short8*)dl = sl;
    }
    __syncthreads();

    // ---- MFMA phase -------------------------------------------------------
    int lane = t & 63;
    int w    = t >> 6;                        // wave: rows w*32..w*32+31
    int lr   = lane & 15;                     // row within 16x16 tile
    int lk   = lane >> 4;                     // k sub-chunk 0..3

    short8 ah[2][2], al[2][2];                // [rt][kh]
    #pragma unroll
    for (int rt = 0; rt < 2; ++rt)
        #pragma unroll
        for (int kh = 0; kh < 2; ++kh) {
            int rl = w * 32 + rt * 16 + lr;
            int cs = (kh * 4 + lk) ^ (rl & 7);
            ah[rt][kh] = *(const short8*)&Ah[rl][cs * 8];
            al[rt][kh] = *(const short8*)&Al[rl][cs * 8];
        }

    f32x4 acc[2][8];
    #pragma unroll
    for (int rt = 0; rt < 2; ++rt)
        #pragma unroll
        for (int ct = 0; ct < 8; ++ct)
            acc[rt][ct] = (f32x4){0.f, 0.f, 0.f, 0.f};

    #pragma unroll
    for (int ct = 0; ct < 8; ++ct) {
        short8 bh[2], bl[2];
        #pragma unroll
        for (int kh = 0; kh < 2; ++kh) {
            int rl = ct * 16 + lr;
            int cs = (kh * 4 + lk) ^ (rl & 7);
            bh[kh] = *(const short8*)&Bh[rl][cs * 8];
            bl[kh] = *(const short8*)&Bl[rl][cs * 8];
        }
        #pragma unroll
        for (int rt = 0; rt < 2; ++rt) {
            #pragma unroll
            for (int kh = 0; kh < 2; ++kh) {
                acc[rt][ct] = __builtin_amdgcn_mfma_f32_16x16x32_bf16(
                    ah[rt][kh], bh[kh], acc[rt][ct], 0, 0, 0);
                acc[rt][ct] = __builtin_amdgcn_mfma_f32_16x16x32_bf16(
                    ah[rt][kh], bl[kh], acc[rt][ct], 0, 0, 0);
                acc[rt][ct] = __builtin_amdgcn_mfma_f32_16x16x32_bf16(
                    al[rt][kh], bh[kh], acc[rt][ct], 0, 0, 0);
            }
        }
    }

    // ---- epilogue: sigmoid + store. C/D: col=lane&15, row=(lane>>4)*4+reg -
    #pragma unroll
    for (int rt = 0; rt < 2; ++rt) {
        #pragma unroll
        for (int ct = 0; ct < 8; ++ct) {
            int gcol = j0 + ct * 16 + lr;
            #pragma unroll
            for (int rg = 0; rg < 4; ++rg) {
                int grow = i0 + w * 32 + rt * 16 + lk * 4 + rg;
                float v  = acc[rt][ct][rg];
                out[(size_t)grow * N_NODES + gcol] = 1.f / (1.f + __expf(-v));
            }
        }
    }
}

// ---------------------------------------------------------------------------
extern "C" void kernel_launch(void* const* d_in, const int* in_sizes, int n_in,
                              void* d_out, int out_size, void* d_ws, size_t ws_size,
                              hipStream_t stream) {
    const void* x  = d_in[0];                 // fp32 [128][8192]
    const int*  ei = (const int*)d_in[1];     // int64 or int32 [2][262144]
    const void* W  = d_in[2];                 // fp32 [128][64]
    const void* b  = d_in[3];                 // fp32 [64]
    float* out = (float*)d_out;               // fp32 [8192][8192]

    char* ws = (char*)d_ws;
    int*   deg    = (int*)ws;                         // 32 KB
    int*   eflag  = (int*)(ws + 32768);               // 4 B
    int*   xdt    = (int*)(ws + 32784);               // 4 B
    int*   offs   = (int*)(ws + 36864);               // 8193*4 B
    int*   cursor = (int*)(ws + 73728);               // 32 KB
    float* dinv   = (float*)(ws + 110592);            // 32 KB
    int*   esrc   = (int*)(ws + 147456);              // 1 MB
    float* h      = (float*)(ws + 1196032);           // 2 MB
    float* z      = (float*)(ws + 3293184);           // 2 MB (ends ~5.14 MB)

    hipMemsetAsync(ws, 0, 36864, stream);             // deg + flags
    detect_ei_kernel<<<32, 256, 0, stream>>>(ei, eflag);
    detect_xdt_kernel<<<1, 256, 0, stream>>>((const u32*)x, xdt);
    deg_kernel<<<N_EDGES / 256, 256, 0, stream>>>(ei, eflag, deg);
    scan_kernel<<<1, 1024, 0, stream>>>(deg, offs, cursor);
    fill_kernel<<<N_EDGES / 256, 256, 0, stream>>>(ei, eflag, cursor, esrc);
    feat_kernel<<<256, 256, 0, stream>>>(x, W, b, xdt, deg, dinv, h, z);
    gather_kernel<<<N_NODES * 64 / 256, 256, 0, stream>>>(offs, esrc, h, dinv, z);
    gemm_sig_kernel<<<dim3(64, 64), 256, 0, stream>>>(z, out);
}

// Round 2
// 344.179 us; speedup vs baseline: 1.2815x; 1.0163x over previous
//
#include <hip/hip_runtime.h>
#include <hip/hip_bf16.h>

#define N_NODES 8192
#define F_IN    128
#define F_OUT   64
#define N_EDGES 262144

typedef unsigned int   u32;
typedef unsigned short u16;
typedef __attribute__((ext_vector_type(8))) short short8;
typedef __attribute__((ext_vector_type(4))) float f32x4;

__device__ __forceinline__ u16 f2bf_rne(float f) {
    u32 u = __float_as_uint(f);
    u32 r = (u + 0x7FFFu + ((u >> 16) & 1u)) >> 16;
    return (u16)r;
}
__device__ __forceinline__ float bf2f(u16 b) {
    return __uint_as_float(((u32)b) << 16);
}

// ---------------------------------------------------------------------------
// Merged detection: blocks 0..31 detect edge_index width (int64 => odd words
// all zero); block 32 detects x dtype (bf16 vs fp32 hedge).
// ---------------------------------------------------------------------------
__global__ __launch_bounds__(256) void detect_kernel(const int* __restrict__ ei,
                                                     const u32* __restrict__ xw,
                                                     int* __restrict__ eflag,
                                                     int* __restrict__ xdt) {
    if (blockIdx.x < 32) {
        int i = blockIdx.x * 256 + threadIdx.x;      // 8192 samples
        if (ei[2 * i + 1] != 0) atomicOr(eflag, 1);
    } else {
        __shared__ int cnt;
        if (threadIdx.x == 0) cnt = 0;
        __syncthreads();
        u32 w = xw[threadIdx.x * 64 + 1];
        u32 e = (w >> 7) & 0xFFu;
        if (e >= 100u && e <= 134u) atomicAdd(&cnt, 1);
        __syncthreads();
        if (threadIdx.x == 0) *xdt = (cnt > 128) ? 1 : 0;
    }
}

// deg[d] = count of incoming edges (self loop added later as +1)
__global__ __launch_bounds__(256) void deg_kernel(const int* __restrict__ ei,
                                                  const int* __restrict__ eflagp,
                                                  int* __restrict__ deg) {
    int e = blockIdx.x * 256 + threadIdx.x;
    bool is64 = (*eflagp == 0);
    int d = is64 ? ei[2 * (N_EDGES + e)] : ei[N_EDGES + e];
    atomicAdd(&deg[d], 1);
}

// ---------------------------------------------------------------------------
// Exclusive prefix sum over deg[8192] -> offs[8193]; cursor = copy of offs.
// ---------------------------------------------------------------------------
__global__ __launch_bounds__(1024) void scan_kernel(const int* __restrict__ deg,
                                                    int* __restrict__ offs,
                                                    int* __restrict__ cursor) {
    __shared__ int part[1024];
    int t = threadIdx.x;
    int loc[8];
    int run = 0;
    #pragma unroll
    for (int j = 0; j < 8; ++j) { loc[j] = run; run += deg[t * 8 + j]; }
    part[t] = run;
    __syncthreads();
    for (int d = 1; d < 1024; d <<= 1) {
        int v = (t >= d) ? part[t - d] : 0;
        __syncthreads();
        part[t] += v;
        __syncthreads();
    }
    int pre = part[t] - run;                 // exclusive prefix of this chunk
    #pragma unroll
    for (int j = 0; j < 8; ++j) {
        int v = pre + loc[j];
        offs[t * 8 + j]   = v;
        cursor[t * 8 + j] = v;
    }
    if (t == 1023) offs[8192] = pre + run;   // == N_EDGES
}

// ---------------------------------------------------------------------------
// Merged: blocks 0..1023 bucket edges by dst (CSR fill); blocks 1024..1279
// compute h_scaled = dinv * (x^T W) and z = b + dinv * h_scaled.
// ---------------------------------------------------------------------------
__global__ __launch_bounds__(256) void fill_feat_kernel(
        const int* __restrict__ ei, const int* __restrict__ eflagp,
        int* __restrict__ cursor, int* __restrict__ esrc,
        const void* __restrict__ xv, const void* __restrict__ Wv,
        const void* __restrict__ bv, const int* __restrict__ xdtp,
        const int* __restrict__ deg,
        float* __restrict__ dinv,
        float* __restrict__ h,                  // [N][64], pre-scaled by dinv[n]
        float* __restrict__ z)                  // [N][64]
{
    __shared__ float Wl[F_IN * F_OUT];          // 32 KB
    int t = threadIdx.x;

    if (blockIdx.x < N_EDGES / 256) {
        // ---------------- CSR fill ----------------
        int e = blockIdx.x * 256 + t;
        bool is64 = (*eflagp == 0);
        int s = is64 ? ei[2 * e]             : ei[e];
        int d = is64 ? ei[2 * (N_EDGES + e)] : ei[N_EDGES + e];
        int pos = atomicAdd(&cursor[d], 1);
        esrc[pos] = s;
        return;
    }

    // ---------------- features ----------------
    const bool isbf = (*xdtp != 0);
    if (isbf) {
        const __hip_bfloat16* Wb = (const __hip_bfloat16*)Wv;
        for (int i = t; i < F_IN * F_OUT; i += 256) Wl[i] = (float)Wb[i];
    } else {
        const float* Wf = (const float*)Wv;
        for (int i = t; i < F_IN * F_OUT; i += 256) Wl[i] = Wf[i];
    }
    __syncthreads();

    int id = (blockIdx.x - N_EDGES / 256) * 256 + t;   // 0..65535
    int og = id >> 13;                          // 0..7, uniform within block
    int n  = id & (N_NODES - 1);

    float dv = rsqrtf((float)(deg[n] + 1));
    float acc[8] = {0.f,0.f,0.f,0.f,0.f,0.f,0.f,0.f};

    if (isbf) {
        const __hip_bfloat16* xb = (const __hip_bfloat16*)xv;
        for (int f = 0; f < F_IN; ++f) {
            float xval = (float)xb[f * N_NODES + n];
            const float4* w4 = (const float4*)&Wl[f * F_OUT + og * 8];
            float4 w0 = w4[0], w1 = w4[1];
            acc[0] += xval * w0.x; acc[1] += xval * w0.y;
            acc[2] += xval * w0.z; acc[3] += xval * w0.w;
            acc[4] += xval * w1.x; acc[5] += xval * w1.y;
            acc[6] += xval * w1.z; acc[7] += xval * w1.w;
        }
    } else {
        const float* xf = (const float*)xv;
        for (int f = 0; f < F_IN; ++f) {
            float xval = xf[f * N_NODES + n];
            const float4* w4 = (const float4*)&Wl[f * F_OUT + og * 8];
            float4 w0 = w4[0], w1 = w4[1];
            acc[0] += xval * w0.x; acc[1] += xval * w0.y;
            acc[2] += xval * w0.z; acc[3] += xval * w0.w;
            acc[4] += xval * w1.x; acc[5] += xval * w1.y;
            acc[6] += xval * w1.z; acc[7] += xval * w1.w;
        }
    }

    if (og == 0) dinv[n] = dv;

    float bvals[8];
    if (isbf) {
        const __hip_bfloat16* bb = (const __hip_bfloat16*)bv;
        #pragma unroll
        for (int j = 0; j < 8; ++j) bvals[j] = (float)bb[og * 8 + j];
    } else {
        const float* bf = (const float*)bv;
        #pragma unroll
        for (int j = 0; j < 8; ++j) bvals[j] = bf[og * 8 + j];
    }
    float hs[8], zb[8];
    #pragma unroll
    for (int j = 0; j < 8; ++j) {
        hs[j] = dv * acc[j];                    // pre-scaled message
        zb[j] = bvals[j] + dv * hs[j];          // self-loop term
    }
    float* hp = h + (size_t)n * 64 + og * 8;
    ((float4*)hp)[0] = make_float4(hs[0], hs[1], hs[2], hs[3]);
    ((float4*)hp)[1] = make_float4(hs[4], hs[5], hs[6], hs[7]);
    float* zp = z + (size_t)n * 64 + og * 8;
    ((float4*)zp)[0] = make_float4(zb[0], zb[1], zb[2], zb[3]);
    ((float4*)zp)[1] = make_float4(zb[4], zb[5], zb[6], zb[7]);
}

// ---------------------------------------------------------------------------
// Gather aggregation: one wave per dst node, no atomics.
// ---------------------------------------------------------------------------
__global__ __launch_bounds__(256) void gather_kernel(
        const int* __restrict__ offs, const int* __restrict__ esrc,
        const float* __restrict__ h, const float* __restrict__ dinv,
        float* __restrict__ z)
{
    int t = blockIdx.x * 256 + threadIdx.x;
    int d = t >> 6;
    int o = t & 63;
    int beg = offs[d], end = offs[d + 1];
    float acc = 0.f;
    for (int i = beg; i < end; ++i) {
        int s = esrc[i];                         // wave-uniform
        acc += h[(size_t)s * 64 + o];            // coalesced 256B row
    }
    z[(size_t)d * 64 + o] += dinv[d] * acc;
}

// ---------------------------------------------------------------------------
// out = sigmoid(z @ z^T) via split-bf16 MFMA, exploiting symmetry:
// 2080 triangular blocks (bi >= bj). Each computes a 128x128 tile, stores it
// directly (scalar, 64B segments) and stores the mirrored tile via an
// LDS transpose (pad-129) with float4 coalesced stores.
// Sigmoid = v_exp + v_rcp (no IEEE div expansion).
// ---------------------------------------------------------------------------
__global__ __launch_bounds__(256) void gemm_sig_kernel(
        const float* __restrict__ z, float* __restrict__ out)
{
    // staging (64 KB) aliased with f32 transpose tile (66 KB)
    __shared__ __align__(16) char smem[128 * 129 * 4];
    u16 (*Ah)[64] = (u16(*)[64])(smem);
    u16 (*Al)[64] = (u16(*)[64])(smem + 16384);
    u16 (*Bh)[64] = (u16(*)[64])(smem + 32768);
    u16 (*Bl)[64] = (u16(*)[64])(smem + 49152);
    float (*Cs)[129] = (float(*)[129])(smem);

    int t = threadIdx.x;

    // triangular decode: blockIdx.x -> (bi, bj), bi >= bj
    int tgt = blockIdx.x;
    int bi = (int)((sqrtf(8.f * (float)tgt + 1.f) - 1.f) * 0.5f);
    while ((bi + 1) * (bi + 2) / 2 <= tgt) ++bi;
    while (bi * (bi + 1) / 2 > tgt) --bi;
    int bj = tgt - bi * (bi + 1) / 2;
    int i0 = bi * 128;
    int j0 = bj * 128;
    bool offdiag = (bi != bj);

    // ---- stage: 2048 items (2 tiles x 128 rows x 8 chunks of 8 floats) ----
    #pragma unroll
    for (int it = 0; it < 8; ++it) {
        int item = it * 256 + t;              // 0..2047
        int tile = item >> 10;                // 0: A(i0), 1: B(j0)
        int r    = (item >> 3) & 127;
        int c    = item & 7;                  // 8-float chunk -> 16B of bf16
        const float* src = z + (size_t)((tile ? j0 : i0) + r) * 64 + c * 8;
        float4 v0 = ((const float4*)src)[0];
        float4 v1 = ((const float4*)src)[1];
        float vf[8] = {v0.x, v0.y, v0.z, v0.w, v1.x, v1.y, v1.z, v1.w};
        short8 sh, sl;
        #pragma unroll
        for (int j = 0; j < 8; ++j) {
            float f  = vf[j];
            u16 hb   = f2bf_rne(f);
            u16 lb   = f2bf_rne(f - bf2f(hb));
            sh[j] = (short)hb;
            sl[j] = (short)lb;
        }
        int cs = c ^ (r & 7);                 // XOR swizzle within row
        u16* dh = tile ? &Bh[r][cs * 8] : &Ah[r][cs * 8];
        u16* dl = tile ? &Bl[r][cs * 8] : &Al[r][cs * 8];
        *(short8*)dh = sh;
        *(short8*)dl = sl;
    }
    __syncthreads();

    // ---- MFMA phase -------------------------------------------------------
    int lane = t & 63;
    int w    = t >> 6;                        // wave: rows w*32..w*32+31
    int lr   = lane & 15;                     // row within 16x16 tile
    int lk   = lane >> 4;                     // k sub-chunk 0..3

    short8 ah[2][2], al[2][2];                // [rt][kh]
    #pragma unroll
    for (int rt = 0; rt < 2; ++rt)
        #pragma unroll
        for (int kh = 0; kh < 2; ++kh) {
            int rl = w * 32 + rt * 16 + lr;
            int cs = (kh * 4 + lk) ^ (rl & 7);
            ah[rt][kh] = *(const short8*)&Ah[rl][cs * 8];
            al[rt][kh] = *(const short8*)&Al[rl][cs * 8];
        }

    f32x4 acc[2][8];
    #pragma unroll
    for (int rt = 0; rt < 2; ++rt)
        #pragma unroll
        for (int ct = 0; ct < 8; ++ct)
            acc[rt][ct] = (f32x4){0.f, 0.f, 0.f, 0.f};

    #pragma unroll
    for (int ct = 0; ct < 8; ++ct) {
        short8 bh[2], bl[2];
        #pragma unroll
        for (int kh = 0; kh < 2; ++kh) {
            int rl = ct * 16 + lr;
            int cs = (kh * 4 + lk) ^ (rl & 7);
            bh[kh] = *(const short8*)&Bh[rl][cs * 8];
            bl[kh] = *(const short8*)&Bl[rl][cs * 8];
        }
        #pragma unroll
        for (int rt = 0; rt < 2; ++rt) {
            #pragma unroll
            for (int kh = 0; kh < 2; ++kh) {
                acc[rt][ct] = __builtin_amdgcn_mfma_f32_16x16x32_bf16(
                    ah[rt][kh], bh[kh], acc[rt][ct], 0, 0, 0);
                acc[rt][ct] = __builtin_amdgcn_mfma_f32_16x16x32_bf16(
                    ah[rt][kh], bl[kh], acc[rt][ct], 0, 0, 0);
                acc[rt][ct] = __builtin_amdgcn_mfma_f32_16x16x32_bf16(
                    al[rt][kh], bh[kh], acc[rt][ct], 0, 0, 0);
            }
        }
    }

    // ---- sigmoid in-register (exp + rcp, no div expansion) ----------------
    #pragma unroll
    for (int rt = 0; rt < 2; ++rt)
        #pragma unroll
        for (int ct = 0; ct < 8; ++ct)
            #pragma unroll
            for (int rg = 0; rg < 4; ++rg) {
                float v = acc[rt][ct][rg];
                acc[rt][ct][rg] =
                    __builtin_amdgcn_rcpf(1.f + __expf(-v));
            }

    // ---- mirrored tile: stage sigmoid values into padded f32 LDS ----------
    if (offdiag) {
        __syncthreads();          // all frag reads done; safe to alias smem
        #pragma unroll
        for (int rt = 0; rt < 2; ++rt)
            #pragma unroll
            for (int ct = 0; ct < 8; ++ct) {
                int col = ct * 16 + lr;
                int row = w * 32 + rt * 16 + lk * 4;
                #pragma unroll
                for (int rg = 0; rg < 4; ++rg)
                    Cs[row + rg][col] = acc[rt][ct][rg];
            }
    }

    // ---- direct stores of the (i0,j0) tile: C/D layout, 64B segments ------
    #pragma unroll
    for (int rt = 0; rt < 2; ++rt)
        #pragma unroll
        for (int ct = 0; ct < 8; ++ct) {
            int gcol = j0 + ct * 16 + lr;
            #pragma unroll
            for (int rg = 0; rg < 4; ++rg) {
                int grow = i0 + w * 32 + rt * 16 + lk * 4 + rg;
                out[(size_t)grow * N_NODES + gcol] = acc[rt][ct][rg];
            }
        }

    // ---- transposed float4 stores of the (j0,i0) tile ---------------------
    if (offdiag) {
        __syncthreads();
        #pragma unroll
        for (int u = 0; u < 16; ++u) {
            int q   = u * 256 + t;          // 0..4095
            int rr  = q >> 5;               // out^T row = LDS column, 0..127
            int cc4 = (q & 31) * 4;         // LDS row start, 0..124
            float4 v = make_float4(Cs[cc4 + 0][rr], Cs[cc4 + 1][rr],
                                   Cs[cc4 + 2][rr], Cs[cc4 + 3][rr]);
            *(float4*)(out + (size_t)(j0 + rr) * N_NODES + i0 + cc4) = v;
        }
    }
}

// ---------------------------------------------------------------------------
extern "C" void kernel_launch(void* const* d_in, const int* in_sizes, int n_in,
                              void* d_out, int out_size, void* d_ws, size_t ws_size,
                              hipStream_t stream) {
    const void* x  = d_in[0];                 // fp32 [128][8192]
    const int*  ei = (const int*)d_in[1];     // int64 or int32 [2][262144]
    const void* W  = d_in[2];                 // fp32 [128][64]
    const void* b  = d_in[3];                 // fp32 [64]
    float* out = (float*)d_out;               // fp32 [8192][8192]

    char* ws = (char*)d_ws;
    int*   deg    = (int*)ws;                         // 32 KB
    int*   eflag  = (int*)(ws + 32768);               // 4 B
    int*   xdt    = (int*)(ws + 32784);               // 4 B
    int*   offs   = (int*)(ws + 36864);               // 8193*4 B
    int*   cursor = (int*)(ws + 73728);               // 32 KB
    float* dinv   = (float*)(ws + 110592);            // 32 KB
    int*   esrc   = (int*)(ws + 147456);              // 1 MB
    float* h      = (float*)(ws + 1196032);           // 2 MB
    float* z      = (float*)(ws + 3293184);           // 2 MB (ends ~5.14 MB)

    hipMemsetAsync(ws, 0, 36864, stream);             // deg + flags
    detect_kernel<<<33, 256, 0, stream>>>(ei, (const u32*)x, eflag, xdt);
    deg_kernel<<<N_EDGES / 256, 256, 0, stream>>>(ei, eflag, deg);
    scan_kernel<<<1, 1024, 0, stream>>>(deg, offs, cursor);
    fill_feat_kernel<<<N_EDGES / 256 + 256, 256, 0, stream>>>(
        ei, eflag, cursor, esrc, x, W, b, xdt, deg, dinv, h, z);
    gather_kernel<<<N_NODES * 64 / 256, 256, 0, stream>>>(offs, esrc, h, dinv, z);
    gemm_sig_kernel<<<64 * 65 / 2, 256, 0, stream>>>(z, out);
}